// Round 9
// baseline (1108.551 us; speedup 1.0000x reference)
//
#include <hip/hip_runtime.h>
#include <hip/hip_fp16.h>

#define C 128
#define C2 64    // half2 per row
#define NBUCK 256
#define NSLICE 8
#define NCHUNK 4          // channel chunks: 32 ch = 64 B fp16 per node per chunk
#define DUMMY_LDS 40960   // caps occupancy at 4 blocks/CU -> ~2.1 MB live gather set

typedef float f4_t __attribute__((ext_vector_type(4)));

// ---------------------------------------------------------------------------
__global__ void zero_cnt_kernel(int* __restrict__ cnt, int n) {
    int i = blockIdx.x * blockDim.x + threadIdx.x;
    if (i < n) cnt[i] = 0;
}

// sliced count: block b handles dst-slice b&7 only -> XCD-local atomics
__global__ void count_kernel(const int* __restrict__ dst, int* __restrict__ cnt,
                             int E, int nps) {
    int slice = blockIdx.x & 7;
    int chunk = blockIdx.x >> 3;
    int nchunks = gridDim.x >> 3;
    int per = (E + nchunks - 1) / nchunks;
    int beg = chunk * per;
    int end = beg + per; if (end > E) end = E;
    int lo = slice * nps, hi = lo + nps;
    for (int e = beg + threadIdx.x; e < end; e += blockDim.x) {
        int d = dst[e];
        if (d >= lo && d < hi) atomicAdd(&cnt[d], 1);
    }
}

// ---- 3-phase parallel exclusive scan of cnt[0..n) --------------------------
__global__ void scan_reduce_kernel(const int* __restrict__ cnt, int* __restrict__ psum, int n) {
    __shared__ int s[256];
    int t = threadIdx.x;
    int i = blockIdx.x * 256 + t;
    s[t] = (i < n) ? cnt[i] : 0;
    __syncthreads();
    for (int off = 128; off > 0; off >>= 1) {
        if (t < off) s[t] += s[t + off];
        __syncthreads();
    }
    if (t == 0) psum[blockIdx.x] = s[0];
}

__global__ void scan_partials_kernel(const int* __restrict__ psum, int* __restrict__ bpre,
                                     int* __restrict__ offsets, int n, int nb) {
    __shared__ int s[256];
    int t = threadIdx.x;
    s[t] = (t < nb) ? psum[t] : 0;
    __syncthreads();
    for (int off = 1; off < 256; off <<= 1) {
        int v = 0;
        if (t >= off) v = s[t - off];
        __syncthreads();
        if (t >= off) s[t] += v;
        __syncthreads();
    }
    bpre[t] = (t == 0) ? 0 : s[t - 1];
    if (t == 255) offsets[n] = s[255];
}

__global__ void scan_apply_kernel(const int* __restrict__ cnt, const int* __restrict__ bpre,
                                  int* __restrict__ offsets, int* __restrict__ cursor,
                                  float* __restrict__ dinv, int n) {
    __shared__ int s[256];
    int t = threadIdx.x;
    int i = blockIdx.x * 256 + t;
    int c = (i < n) ? cnt[i] : 0;
    s[t] = c;
    __syncthreads();
    for (int off = 1; off < 256; off <<= 1) {
        int v = 0;
        if (t >= off) v = s[t - off];
        __syncthreads();
        if (t >= off) s[t] += v;
        __syncthreads();
    }
    if (i < n) {
        int excl = bpre[blockIdx.x] + s[t] - c;
        offsets[i] = excl;
        cursor[i]  = excl;
        dinv[i]    = rsqrtf((float)(c + 1));
    }
}

// ---- degree bucket sort -> perm (ascending degree) -------------------------
__global__ void hist_zero_kernel(int* __restrict__ hist) { hist[threadIdx.x] = 0; }

__global__ void hist_kernel(const int* __restrict__ cnt, int* __restrict__ hist, int n) {
    __shared__ int lh[NBUCK];
    int t = threadIdx.x;
    lh[t] = 0;
    __syncthreads();
    for (int i = blockIdx.x * blockDim.x + t; i < n; i += gridDim.x * blockDim.x) {
        int d = cnt[i]; if (d > NBUCK - 1) d = NBUCK - 1;
        atomicAdd(&lh[d], 1);
    }
    __syncthreads();
    int c = lh[t];
    if (c) atomicAdd(&hist[t], c);
}

__global__ void hist_scan_kernel(const int* __restrict__ hist, int* __restrict__ bcur) {
    __shared__ int s[256];
    int t = threadIdx.x;
    s[t] = hist[t];
    __syncthreads();
    for (int off = 1; off < 256; off <<= 1) {
        int v = 0;
        if (t >= off) v = s[t - off];
        __syncthreads();
        if (t >= off) s[t] += v;
        __syncthreads();
    }
    bcur[t] = (t == 0) ? 0 : s[t - 1];
}

__global__ void perm_kernel(const int* __restrict__ cnt, int* __restrict__ bcur,
                            int* __restrict__ perm, int n) {
    __shared__ int lhist[NBUCK];
    __shared__ int lbase[NBUCK];
    int t = threadIdx.x;
    lhist[t] = 0;
    __syncthreads();
    int i = blockIdx.x * 256 + t;
    int d = 0, lr = 0;
    if (i < n) {
        d = cnt[i]; if (d > NBUCK - 1) d = NBUCK - 1;
        lr = atomicAdd(&lhist[d], 1);
    }
    __syncthreads();
    int c = lhist[t];
    if (c > 0) lbase[t] = atomicAdd(&bcur[t], c);
    __syncthreads();
    if (i < n) perm[lbase[d] + lr] = i;
}

// ---- sliced counting-sort scatter: XCD-local CSR writes --------------------
__global__ void scatter_kernel(const int* __restrict__ src, const int* __restrict__ dst,
                               int* __restrict__ cursor, int* __restrict__ sorted_src,
                               int E, int nps) {
    int slice = blockIdx.x & 7;
    int chunk = blockIdx.x >> 3;
    int nchunks = gridDim.x >> 3;
    int per = (E + nchunks - 1) / nchunks;
    int beg = chunk * per;
    int end = beg + per; if (end > E) end = E;
    int lo = slice * nps, hi = lo + nps;
    for (int e = beg + threadIdx.x; e < end; e += blockDim.x) {
        int d = dst[e];
        if (d >= lo && d < hi) {
            int pos = atomicAdd(&cursor[d], 1);
            sorted_src[pos] = src[e];
        }
    }
}

// hidden = coeffs[0]*x (fp32, natural layout); y0 = half(dinv*x) in CHUNK-MAJOR
// layout: y[chunk][node][32ch]. One thread per 4 channels (uint2 of half4).
__global__ void init_kernel(const float* __restrict__ x, const float* __restrict__ coeffs,
                            const float* __restrict__ dinv, float* __restrict__ hidden,
                            unsigned short* __restrict__ y0, int N) {
    int i = blockIdx.x * blockDim.x + threadIdx.x;   // uint2 id over N*32
    if (i >= N * 32) return;
    int node = i >> 5;
    int q = i & 31;            // which 4-channel group within the row
    float dv = dinv[node];
    float4 xv = ((const float4*)x)[i];
    float g0 = coeffs[0];
    ((float4*)hidden)[i] = make_float4(g0 * xv.x, g0 * xv.y, g0 * xv.z, g0 * xv.w);
    int chunk = q >> 3, jj = q & 7;
    __half2 p0 = __floats2half2_rn(dv * xv.x, dv * xv.y);
    __half2 p1 = __floats2half2_rn(dv * xv.z, dv * xv.w);
    uint2 u;
    u.x = *reinterpret_cast<unsigned int*>(&p0);
    u.y = *reinterpret_cast<unsigned int*>(&p1);
    ((uint2*)y0)[((size_t)chunk * N + node) * 8 + jj] = u;
}

// ---------------------------------------------------------------------------
__device__ __forceinline__ void acc4(float* a, uint2 u) {
    __half2 p = *reinterpret_cast<__half2*>(&u.x);
    __half2 q = *reinterpret_cast<__half2*>(&u.y);
    float2 f = __half22float2(p);
    float2 g = __half22float2(q);
    a[0] += f.x; a[1] += f.y; a[2] += g.x; a[3] += g.y;
}

// one propagation step, chunk-phased across the grid.
// chunk = blockIdx / bpc; within chunk, block = 32 nodes (8 lanes x 8 B row slice).
// Grid-order dispatch keeps ~1 chunk (3.2 MB) hot in every XCD L2 at a time;
// DUMMY_LDS caps occupancy at 4 blocks/CU -> live gather set ~2.1 MB.
__global__ __launch_bounds__(256)
void prop_kernel(const unsigned short* __restrict__ yin, unsigned short* __restrict__ yout,
                 float* __restrict__ hidden, const float* __restrict__ coeffs, int k,
                 const int* __restrict__ offsets, const int* __restrict__ srcs,
                 const float* __restrict__ dinv, const int* __restrict__ perm,
                 int n, int bpc) {
    extern __shared__ char dummy[];   // occupancy cap only
    (void)dummy;
    int t = threadIdx.x;
    int lane = t & 63;
    int grp  = lane >> 3;          // node within wave: 0..7
    int j    = lane & 7;           // 8-B slice within 64-B chunk row
    int chunk = blockIdx.x / bpc;
    int slot  = (blockIdx.x % bpc) * 32 + (t >> 6) * 8 + grp;
    if (slot >= n) return;
    int v = perm[slot];
    int beg = offsets[v];
    int end = offsets[v + 1];
    float dv = dinv[v];
    float gamma = coeffs[k];

    const uint2* ybase = (const uint2*)yin + (size_t)chunk * n * 8;  // chunk base
    float A0[4] = {0,0,0,0}, A1[4] = {0,0,0,0}, A2[4] = {0,0,0,0}, A3[4] = {0,0,0,0};

    int e = beg;
    for (; e + 8 <= end; e += 8) {
        int s0 = __builtin_nontemporal_load(srcs + e);
        int s1 = __builtin_nontemporal_load(srcs + e + 1);
        int s2 = __builtin_nontemporal_load(srcs + e + 2);
        int s3 = __builtin_nontemporal_load(srcs + e + 3);
        int s4 = __builtin_nontemporal_load(srcs + e + 4);
        int s5 = __builtin_nontemporal_load(srcs + e + 5);
        int s6 = __builtin_nontemporal_load(srcs + e + 6);
        int s7 = __builtin_nontemporal_load(srcs + e + 7);
        uint2 u0 = ybase[(size_t)s0 * 8 + j];
        uint2 u1 = ybase[(size_t)s1 * 8 + j];
        uint2 u2 = ybase[(size_t)s2 * 8 + j];
        uint2 u3 = ybase[(size_t)s3 * 8 + j];
        uint2 u4 = ybase[(size_t)s4 * 8 + j];
        uint2 u5 = ybase[(size_t)s5 * 8 + j];
        uint2 u6 = ybase[(size_t)s6 * 8 + j];
        uint2 u7 = ybase[(size_t)s7 * 8 + j];
        acc4(A0, u0); acc4(A1, u1); acc4(A2, u2); acc4(A3, u3);
        acc4(A0, u4); acc4(A1, u5); acc4(A2, u6); acc4(A3, u7);
    }
    for (; e + 4 <= end; e += 4) {
        int s0 = srcs[e], s1 = srcs[e + 1], s2 = srcs[e + 2], s3 = srcs[e + 3];
        uint2 u0 = ybase[(size_t)s0 * 8 + j];
        uint2 u1 = ybase[(size_t)s1 * 8 + j];
        uint2 u2 = ybase[(size_t)s2 * 8 + j];
        uint2 u3 = ybase[(size_t)s3 * 8 + j];
        acc4(A0, u0); acc4(A1, u1); acc4(A2, u2); acc4(A3, u3);
    }
    for (; e < end; ++e) {
        uint2 u = ybase[(size_t)srcs[e] * 8 + j];
        acc4(A0, u);
    }
    // self-loop term
    uint2 us = ybase[(size_t)v * 8 + j];
    acc4(A1, us);

    float xn[4];
    #pragma unroll
    for (int i = 0; i < 4; ++i)
        xn[i] = dv * ((A0[i] + A1[i]) + (A2[i] + A3[i]));

    // hidden RMW (natural layout; nontemporal stream)
    f4_t* hp = (f4_t*)(hidden + (size_t)v * C + chunk * 32 + j * 4);
    f4_t h = __builtin_nontemporal_load(hp);
    h.x += gamma * xn[0]; h.y += gamma * xn[1]; h.z += gamma * xn[2]; h.w += gamma * xn[3];
    __builtin_nontemporal_store(h, hp);

    // yout (chunk-major), nontemporal so it doesn't evict the current hot chunk
    __half2 p0 = __floats2half2_rn(dv * xn[0], dv * xn[1]);
    __half2 p1 = __floats2half2_rn(dv * xn[2], dv * xn[3]);
    unsigned long long uu =
        (unsigned long long)*reinterpret_cast<unsigned int*>(&p0) |
        ((unsigned long long)*reinterpret_cast<unsigned int*>(&p1) << 32);
    unsigned long long* op =
        (unsigned long long*)((uint2*)yout + (size_t)chunk * n * 8 + (size_t)v * 8 + j);
    __builtin_nontemporal_store(uu, op);
}

extern "C" void kernel_launch(void* const* d_in, const int* in_sizes, int n_in,
                              void* d_out, int out_size, void* d_ws, size_t ws_size,
                              hipStream_t stream) {
    const float* x      = (const float*)d_in[0];
    const float* coeffs = (const float*)d_in[1];
    const int*   edge   = (const int*)d_in[2];

    const int N = in_sizes[0] / C;          // 50000
    const int K = in_sizes[1] - 1;          // 10
    const int E = in_sizes[2] / 2;          // 1,600,000
    const int* src = edge;
    const int* dst = edge + E;

    char* ws = (char*)d_ws;
    auto alloc = [&](size_t bytes) -> void* {
        void* p = (void*)ws;
        ws += (bytes + 255) & ~(size_t)255;
        return p;
    };
    int*            cnt        = (int*)alloc((size_t)N * 4);
    int*            offsets    = (int*)alloc((size_t)(N + 1) * 4);
    int*            cursor     = (int*)alloc((size_t)N * 4);
    int*            sorted_src = (int*)alloc((size_t)E * 4);
    float*          dinv       = (float*)alloc((size_t)N * 4);
    int*            psum       = (int*)alloc(256 * 4);
    int*            bpre       = (int*)alloc(256 * 4);
    int*            hist       = (int*)alloc(NBUCK * 4);
    int*            bcur       = (int*)alloc(NBUCK * 4);
    int*            perm       = (int*)alloc((size_t)N * 4);
    unsigned short* buf0       = (unsigned short*)alloc((size_t)N * C * 2);
    unsigned short* buf1       = (unsigned short*)alloc((size_t)N * C * 2);

    const int B = 256;
    const int nb = (N + 255) / 256;              // 196 scan blocks (<= 256)
    const int nps = (N + NSLICE - 1) / NSLICE;   // 6250 nodes per slice
    const int slice_grid = 8 * 256;              // 8 slices x 256 chunks
    const int bpc = (N + 31) / 32;               // 1563 blocks per channel-chunk

    zero_cnt_kernel<<<(N + B - 1) / B, B, 0, stream>>>(cnt, N);
    count_kernel<<<slice_grid, B, 0, stream>>>(dst, cnt, E, nps);

    scan_reduce_kernel<<<nb, 256, 0, stream>>>(cnt, psum, N);
    scan_partials_kernel<<<1, 256, 0, stream>>>(psum, bpre, offsets, N, nb);
    scan_apply_kernel<<<nb, 256, 0, stream>>>(cnt, bpre, offsets, cursor, dinv, N);

    hist_zero_kernel<<<1, NBUCK, 0, stream>>>(hist);
    hist_kernel<<<64, 256, 0, stream>>>(cnt, hist, N);
    hist_scan_kernel<<<1, NBUCK, 0, stream>>>(hist, bcur);
    perm_kernel<<<nb, 256, 0, stream>>>(cnt, bcur, perm, N);

    scatter_kernel<<<slice_grid, B, 0, stream>>>(src, dst, cursor, sorted_src, E, nps);
    init_kernel<<<((size_t)N * 32 + B - 1) / B, B, 0, stream>>>(x, coeffs, dinv,
                                                                (float*)d_out, buf0, N);

    const unsigned short* yin = buf0;
    unsigned short* yout = buf1;
    for (int k = 1; k <= K; ++k) {
        prop_kernel<<<NCHUNK * bpc, B, DUMMY_LDS, stream>>>(yin, yout, (float*)d_out,
                                                            coeffs, k, offsets, sorted_src,
                                                            dinv, perm, N, bpc);
        yin  = yout;
        yout = (yout == buf0) ? buf1 : buf0;
    }
}

// Round 10
// 854.983 us; speedup vs baseline: 1.2966x; 1.2966x over previous
//
#include <hip/hip_runtime.h>
#include <hip/hip_fp16.h>

#define C 128
#define C2 64    // half2 per row
#define NBUCK 256
#define NSLICE 8

typedef float f4_t __attribute__((ext_vector_type(4)));

// ---------------------------------------------------------------------------
__global__ void zero_cnt_kernel(int* __restrict__ cnt, int n) {
    int i = blockIdx.x * blockDim.x + threadIdx.x;
    if (i < n) cnt[i] = 0;
}

// sliced count: block b handles dst-slice b&7 only -> XCD-local atomics.
// nt loads keep the streaming dst reads from evicting cnt lines.
__global__ void count_kernel(const int* __restrict__ dst, int* __restrict__ cnt,
                             int E, int nps) {
    int slice = blockIdx.x & 7;
    int chunk = blockIdx.x >> 3;
    int nchunks = gridDim.x >> 3;
    int per = (E + nchunks - 1) / nchunks;
    int beg = chunk * per;
    int end = beg + per; if (end > E) end = E;
    int lo = slice * nps, hi = lo + nps;
    for (int e = beg + threadIdx.x; e < end; e += blockDim.x) {
        int d = __builtin_nontemporal_load(dst + e);
        if (d >= lo && d < hi) atomicAdd(&cnt[d], 1);
    }
}

// ---- 3-phase parallel exclusive scan of cnt[0..n) --------------------------
__global__ void scan_reduce_kernel(const int* __restrict__ cnt, int* __restrict__ psum, int n) {
    __shared__ int s[256];
    int t = threadIdx.x;
    int i = blockIdx.x * 256 + t;
    s[t] = (i < n) ? cnt[i] : 0;
    __syncthreads();
    for (int off = 128; off > 0; off >>= 1) {
        if (t < off) s[t] += s[t + off];
        __syncthreads();
    }
    if (t == 0) psum[blockIdx.x] = s[0];
}

__global__ void scan_partials_kernel(const int* __restrict__ psum, int* __restrict__ bpre,
                                     int* __restrict__ offsets, int n, int nb) {
    __shared__ int s[256];
    int t = threadIdx.x;
    s[t] = (t < nb) ? psum[t] : 0;
    __syncthreads();
    for (int off = 1; off < 256; off <<= 1) {
        int v = 0;
        if (t >= off) v = s[t - off];
        __syncthreads();
        if (t >= off) s[t] += v;
        __syncthreads();
    }
    bpre[t] = (t == 0) ? 0 : s[t - 1];
    if (t == 255) offsets[n] = s[255];
}

__global__ void scan_apply_kernel(const int* __restrict__ cnt, const int* __restrict__ bpre,
                                  int* __restrict__ offsets, int* __restrict__ cursor,
                                  float* __restrict__ dinv, int n) {
    __shared__ int s[256];
    int t = threadIdx.x;
    int i = blockIdx.x * 256 + t;
    int c = (i < n) ? cnt[i] : 0;
    s[t] = c;
    __syncthreads();
    for (int off = 1; off < 256; off <<= 1) {
        int v = 0;
        if (t >= off) v = s[t - off];
        __syncthreads();
        if (t >= off) s[t] += v;
        __syncthreads();
    }
    if (i < n) {
        int excl = bpre[blockIdx.x] + s[t] - c;
        offsets[i] = excl;
        cursor[i]  = excl;
        dinv[i]    = rsqrtf((float)(c + 1));
    }
}

// ---- degree bucket sort -> perm (ascending degree) -------------------------
__global__ void hist_zero_kernel(int* __restrict__ hist) { hist[threadIdx.x] = 0; }

__global__ void hist_kernel(const int* __restrict__ cnt, int* __restrict__ hist, int n) {
    __shared__ int lh[NBUCK];
    int t = threadIdx.x;
    lh[t] = 0;
    __syncthreads();
    for (int i = blockIdx.x * blockDim.x + t; i < n; i += gridDim.x * blockDim.x) {
        int d = cnt[i]; if (d > NBUCK - 1) d = NBUCK - 1;
        atomicAdd(&lh[d], 1);
    }
    __syncthreads();
    int c = lh[t];
    if (c) atomicAdd(&hist[t], c);
}

__global__ void hist_scan_kernel(const int* __restrict__ hist, int* __restrict__ bcur) {
    __shared__ int s[256];
    int t = threadIdx.x;
    s[t] = hist[t];
    __syncthreads();
    for (int off = 1; off < 256; off <<= 1) {
        int v = 0;
        if (t >= off) v = s[t - off];
        __syncthreads();
        if (t >= off) s[t] += v;
        __syncthreads();
    }
    bcur[t] = (t == 0) ? 0 : s[t - 1];
}

__global__ void perm_kernel(const int* __restrict__ cnt, int* __restrict__ bcur,
                            int* __restrict__ perm, int n) {
    __shared__ int lhist[NBUCK];
    __shared__ int lbase[NBUCK];
    int t = threadIdx.x;
    lhist[t] = 0;
    __syncthreads();
    int i = blockIdx.x * 256 + t;
    int d = 0, lr = 0;
    if (i < n) {
        d = cnt[i]; if (d > NBUCK - 1) d = NBUCK - 1;
        lr = atomicAdd(&lhist[d], 1);
    }
    __syncthreads();
    int c = lhist[t];
    if (c > 0) lbase[t] = atomicAdd(&bcur[t], c);
    __syncthreads();
    if (i < n) perm[lbase[d] + lr] = i;
}

// ---- sliced counting-sort scatter: XCD-local CSR writes --------------------
// nt loads on the edge streams keep CSR/cursor lines resident until full.
__global__ void scatter_kernel(const int* __restrict__ src, const int* __restrict__ dst,
                               int* __restrict__ cursor, int* __restrict__ sorted_src,
                               int E, int nps) {
    int slice = blockIdx.x & 7;
    int chunk = blockIdx.x >> 3;
    int nchunks = gridDim.x >> 3;
    int per = (E + nchunks - 1) / nchunks;
    int beg = chunk * per;
    int end = beg + per; if (end > E) end = E;
    int lo = slice * nps, hi = lo + nps;
    for (int e = beg + threadIdx.x; e < end; e += blockDim.x) {
        int d = __builtin_nontemporal_load(dst + e);
        if (d >= lo && d < hi) {
            int s = __builtin_nontemporal_load(src + e);
            int pos = atomicAdd(&cursor[d], 1);
            sorted_src[pos] = s;
        }
    }
}

// hidden = coeffs[0]*x (fp32), y0 = half(dinv[v]*x)
__global__ void init_kernel(const float* __restrict__ x, const float* __restrict__ coeffs,
                            const float* __restrict__ dinv, float2* __restrict__ hidden,
                            __half2* __restrict__ y0, int total2) {
    int i = blockIdx.x * blockDim.x + threadIdx.x;
    if (i >= total2) return;
    int v = i >> 6;  // i / C2
    float dv = dinv[v];
    float2 xv = ((const float2*)x)[i];
    float g0 = coeffs[0];
    hidden[i] = make_float2(g0 * xv.x, g0 * xv.y);
    y0[i] = __floats2half2_rn(dv * xv.x, dv * xv.y);
}

// ---------------------------------------------------------------------------
__device__ __forceinline__ void acc8(float* a, uint4 u) {
    __half2* h = (__half2*)&u;
    #pragma unroll
    for (int i = 0; i < 4; ++i) {
        float2 f = __half22float2(h[i]);
        a[2 * i]     += f.x;
        a[2 * i + 1] += f.y;
    }
}

// one propagation step. block = 256 thr = 4 waves = 16 nodes (16 lanes/node).
// lane j owns 16 B = 8 channels; full 256-B rows -> no gather overfetch.
__global__ __launch_bounds__(256)
void prop_kernel(const unsigned short* __restrict__ yin, unsigned short* __restrict__ yout,
                 float* __restrict__ hidden, const float* __restrict__ coeffs, int k,
                 const int* __restrict__ offsets, const int* __restrict__ srcs,
                 const float* __restrict__ dinv, const int* __restrict__ perm, int n) {
    int t = threadIdx.x;
    int lane = t & 63;
    int grp  = lane >> 4;          // node within wave: 0..3
    int j    = lane & 15;          // 16-B slice within row: 0..15
    int slot = blockIdx.x * 16 + (t >> 6) * 4 + grp;
    if (slot >= n) return;
    int v = perm[slot];
    int beg = offsets[v];
    int end = offsets[v + 1];
    float dv = dinv[v];
    float gamma = coeffs[k];

    const uint4* base = (const uint4*)yin;   // row = 16 uint4 (256 B)
    float A0[8] = {0,0,0,0,0,0,0,0};
    float A1[8] = {0,0,0,0,0,0,0,0};
    float A2[8] = {0,0,0,0,0,0,0,0};
    float A3[8] = {0,0,0,0,0,0,0,0};

    int e = beg;
    for (; e + 8 <= end; e += 8) {
        int s0 = srcs[e],     s1 = srcs[e + 1], s2 = srcs[e + 2], s3 = srcs[e + 3];
        int s4 = srcs[e + 4], s5 = srcs[e + 5], s6 = srcs[e + 6], s7 = srcs[e + 7];
        uint4 u0 = base[(size_t)s0 * 16 + j];
        uint4 u1 = base[(size_t)s1 * 16 + j];
        uint4 u2 = base[(size_t)s2 * 16 + j];
        uint4 u3 = base[(size_t)s3 * 16 + j];
        uint4 u4 = base[(size_t)s4 * 16 + j];
        uint4 u5 = base[(size_t)s5 * 16 + j];
        uint4 u6 = base[(size_t)s6 * 16 + j];
        uint4 u7 = base[(size_t)s7 * 16 + j];
        acc8(A0, u0); acc8(A1, u1); acc8(A2, u2); acc8(A3, u3);
        acc8(A0, u4); acc8(A1, u5); acc8(A2, u6); acc8(A3, u7);
    }
    for (; e + 4 <= end; e += 4) {
        int s0 = srcs[e], s1 = srcs[e + 1], s2 = srcs[e + 2], s3 = srcs[e + 3];
        uint4 u0 = base[(size_t)s0 * 16 + j];
        uint4 u1 = base[(size_t)s1 * 16 + j];
        uint4 u2 = base[(size_t)s2 * 16 + j];
        uint4 u3 = base[(size_t)s3 * 16 + j];
        acc8(A0, u0); acc8(A1, u1); acc8(A2, u2); acc8(A3, u3);
    }
    for (; e < end; ++e) {
        uint4 u = base[(size_t)srcs[e] * 16 + j];
        acc8(A0, u);
    }
    // self-loop term
    uint4 us = base[(size_t)v * 16 + j];
    acc8(A1, us);

    float xn[8];
    #pragma unroll
    for (int i = 0; i < 8; ++i)
        xn[i] = dv * ((A0[i] + A1[i]) + (A2[i] + A3[i]));

    // hidden RMW (pure stream; nontemporal to protect cache residency of y)
    f4_t* hp = (f4_t*)(hidden + (size_t)v * C + j * 8);
    f4_t h0 = __builtin_nontemporal_load(hp);
    f4_t h1 = __builtin_nontemporal_load(hp + 1);
    h0.x += gamma * xn[0]; h0.y += gamma * xn[1]; h0.z += gamma * xn[2]; h0.w += gamma * xn[3];
    h1.x += gamma * xn[4]; h1.y += gamma * xn[5]; h1.z += gamma * xn[6]; h1.w += gamma * xn[7];
    __builtin_nontemporal_store(h0, hp);
    __builtin_nontemporal_store(h1, hp + 1);

    // yout = half(dinv * xn)
    __half2 p0 = __floats2half2_rn(dv * xn[0], dv * xn[1]);
    __half2 p1 = __floats2half2_rn(dv * xn[2], dv * xn[3]);
    __half2 p2 = __floats2half2_rn(dv * xn[4], dv * xn[5]);
    __half2 p3 = __floats2half2_rn(dv * xn[6], dv * xn[7]);
    uint4 u;
    u.x = *reinterpret_cast<unsigned int*>(&p0);
    u.y = *reinterpret_cast<unsigned int*>(&p1);
    u.z = *reinterpret_cast<unsigned int*>(&p2);
    u.w = *reinterpret_cast<unsigned int*>(&p3);
    ((uint4*)yout)[(size_t)v * 16 + j] = u;
}

extern "C" void kernel_launch(void* const* d_in, const int* in_sizes, int n_in,
                              void* d_out, int out_size, void* d_ws, size_t ws_size,
                              hipStream_t stream) {
    const float* x      = (const float*)d_in[0];
    const float* coeffs = (const float*)d_in[1];
    const int*   edge   = (const int*)d_in[2];

    const int N = in_sizes[0] / C;          // 50000
    const int K = in_sizes[1] - 1;          // 10
    const int E = in_sizes[2] / 2;          // 1,600,000
    const int* src = edge;
    const int* dst = edge + E;

    char* ws = (char*)d_ws;
    auto alloc = [&](size_t bytes) -> void* {
        void* p = (void*)ws;
        ws += (bytes + 255) & ~(size_t)255;
        return p;
    };
    int*            cnt        = (int*)alloc((size_t)N * 4);
    int*            offsets    = (int*)alloc((size_t)(N + 1) * 4);
    int*            cursor     = (int*)alloc((size_t)N * 4);
    int*            sorted_src = (int*)alloc((size_t)E * 4);
    float*          dinv       = (float*)alloc((size_t)N * 4);
    int*            psum       = (int*)alloc(256 * 4);
    int*            bpre       = (int*)alloc(256 * 4);
    int*            hist       = (int*)alloc(NBUCK * 4);
    int*            bcur       = (int*)alloc(NBUCK * 4);
    int*            perm       = (int*)alloc((size_t)N * 4);
    unsigned short* buf0       = (unsigned short*)alloc((size_t)N * C * 2);
    unsigned short* buf1       = (unsigned short*)alloc((size_t)N * C * 2);

    const int B = 256;
    const int nb = (N + 255) / 256;              // 196 scan blocks (<= 256)
    const int nps = (N + NSLICE - 1) / NSLICE;   // 6250 nodes per slice
    const int slice_grid = 8 * 256;              // 8 slices x 256 chunks

    zero_cnt_kernel<<<(N + B - 1) / B, B, 0, stream>>>(cnt, N);
    count_kernel<<<slice_grid, B, 0, stream>>>(dst, cnt, E, nps);

    scan_reduce_kernel<<<nb, 256, 0, stream>>>(cnt, psum, N);
    scan_partials_kernel<<<1, 256, 0, stream>>>(psum, bpre, offsets, N, nb);
    scan_apply_kernel<<<nb, 256, 0, stream>>>(cnt, bpre, offsets, cursor, dinv, N);

    hist_zero_kernel<<<1, NBUCK, 0, stream>>>(hist);
    hist_kernel<<<64, 256, 0, stream>>>(cnt, hist, N);
    hist_scan_kernel<<<1, NBUCK, 0, stream>>>(hist, bcur);
    perm_kernel<<<nb, 256, 0, stream>>>(cnt, bcur, perm, N);

    scatter_kernel<<<slice_grid, B, 0, stream>>>(src, dst, cursor, sorted_src, E, nps);
    init_kernel<<<((size_t)N * C2 + B - 1) / B, B, 0, stream>>>(x, coeffs, dinv,
                                                                (float2*)d_out,
                                                                (__half2*)buf0, N * C2);

    const unsigned short* yin = buf0;
    unsigned short* yout = buf1;
    for (int k = 1; k <= K; ++k) {
        prop_kernel<<<(N + 15) / 16, B, 0, stream>>>(yin, yout, (float*)d_out, coeffs, k,
                                                     offsets, sorted_src, dinv, perm, N);
        yin  = yout;
        yout = (yout == buf0) ? buf1 : buf0;
    }
}

// Round 11
// 849.928 us; speedup vs baseline: 1.3043x; 1.0059x over previous
//
#include <hip/hip_runtime.h>
#include <hip/hip_fp16.h>

#define C 128
#define HC 64    // channels per pass
#define NBUCK 256
#define NSLICE 8

typedef float f4_t __attribute__((ext_vector_type(4)));

// ---------------------------------------------------------------------------
__global__ void zero_cnt_kernel(int* __restrict__ cnt, int n) {
    int i = blockIdx.x * blockDim.x + threadIdx.x;
    if (i < n) cnt[i] = 0;
}

// sliced count: block b handles dst-slice b&7 only -> XCD-local atomics
__global__ void count_kernel(const int* __restrict__ dst, int* __restrict__ cnt,
                             int E, int nps) {
    int slice = blockIdx.x & 7;
    int chunk = blockIdx.x >> 3;
    int nchunks = gridDim.x >> 3;
    int per = (E + nchunks - 1) / nchunks;
    int beg = chunk * per;
    int end = beg + per; if (end > E) end = E;
    int lo = slice * nps, hi = lo + nps;
    for (int e = beg + threadIdx.x; e < end; e += blockDim.x) {
        int d = dst[e];
        if (d >= lo && d < hi) atomicAdd(&cnt[d], 1);
    }
}

// ---- 3-phase parallel exclusive scan of cnt[0..n) --------------------------
__global__ void scan_reduce_kernel(const int* __restrict__ cnt, int* __restrict__ psum, int n) {
    __shared__ int s[256];
    int t = threadIdx.x;
    int i = blockIdx.x * 256 + t;
    s[t] = (i < n) ? cnt[i] : 0;
    __syncthreads();
    for (int off = 128; off > 0; off >>= 1) {
        if (t < off) s[t] += s[t + off];
        __syncthreads();
    }
    if (t == 0) psum[blockIdx.x] = s[0];
}

__global__ void scan_partials_kernel(const int* __restrict__ psum, int* __restrict__ bpre,
                                     int* __restrict__ offsets, int n, int nb) {
    __shared__ int s[256];
    int t = threadIdx.x;
    s[t] = (t < nb) ? psum[t] : 0;
    __syncthreads();
    for (int off = 1; off < 256; off <<= 1) {
        int v = 0;
        if (t >= off) v = s[t - off];
        __syncthreads();
        if (t >= off) s[t] += v;
        __syncthreads();
    }
    bpre[t] = (t == 0) ? 0 : s[t - 1];
    if (t == 255) offsets[n] = s[255];
}

__global__ void scan_apply_kernel(const int* __restrict__ cnt, const int* __restrict__ bpre,
                                  int* __restrict__ offsets, int* __restrict__ cursor,
                                  float* __restrict__ dinv, int n) {
    __shared__ int s[256];
    int t = threadIdx.x;
    int i = blockIdx.x * 256 + t;
    int c = (i < n) ? cnt[i] : 0;
    s[t] = c;
    __syncthreads();
    for (int off = 1; off < 256; off <<= 1) {
        int v = 0;
        if (t >= off) v = s[t - off];
        __syncthreads();
        if (t >= off) s[t] += v;
        __syncthreads();
    }
    if (i < n) {
        int excl = bpre[blockIdx.x] + s[t] - c;
        offsets[i] = excl;
        cursor[i]  = excl;
        dinv[i]    = rsqrtf((float)(c + 1));
    }
}

// ---- degree bucket sort -> perm (ascending degree) -------------------------
__global__ void hist_zero_kernel(int* __restrict__ hist) { hist[threadIdx.x] = 0; }

__global__ void hist_kernel(const int* __restrict__ cnt, int* __restrict__ hist, int n) {
    __shared__ int lh[NBUCK];
    int t = threadIdx.x;
    lh[t] = 0;
    __syncthreads();
    for (int i = blockIdx.x * blockDim.x + t; i < n; i += gridDim.x * blockDim.x) {
        int d = cnt[i]; if (d > NBUCK - 1) d = NBUCK - 1;
        atomicAdd(&lh[d], 1);
    }
    __syncthreads();
    int c = lh[t];
    if (c) atomicAdd(&hist[t], c);
}

__global__ void hist_scan_kernel(const int* __restrict__ hist, int* __restrict__ bcur) {
    __shared__ int s[256];
    int t = threadIdx.x;
    s[t] = hist[t];
    __syncthreads();
    for (int off = 1; off < 256; off <<= 1) {
        int v = 0;
        if (t >= off) v = s[t - off];
        __syncthreads();
        if (t >= off) s[t] += v;
        __syncthreads();
    }
    bcur[t] = (t == 0) ? 0 : s[t - 1];
}

__global__ void perm_kernel(const int* __restrict__ cnt, int* __restrict__ bcur,
                            int* __restrict__ perm, int n) {
    __shared__ int lhist[NBUCK];
    __shared__ int lbase[NBUCK];
    int t = threadIdx.x;
    lhist[t] = 0;
    __syncthreads();
    int i = blockIdx.x * 256 + t;
    int d = 0, lr = 0;
    if (i < n) {
        d = cnt[i]; if (d > NBUCK - 1) d = NBUCK - 1;
        lr = atomicAdd(&lhist[d], 1);
    }
    __syncthreads();
    int c = lhist[t];
    if (c > 0) lbase[t] = atomicAdd(&bcur[t], c);
    __syncthreads();
    if (i < n) perm[lbase[d] + lr] = i;
}

// ---- sliced counting-sort scatter: XCD-local CSR writes --------------------
__global__ void scatter_kernel(const int* __restrict__ src, const int* __restrict__ dst,
                               int* __restrict__ cursor, int* __restrict__ sorted_src,
                               int E, int nps) {
    int slice = blockIdx.x & 7;
    int chunk = blockIdx.x >> 3;
    int nchunks = gridDim.x >> 3;
    int per = (E + nchunks - 1) / nchunks;
    int beg = chunk * per;
    int end = beg + per; if (end > E) end = E;
    int lo = slice * nps, hi = lo + nps;
    for (int e = beg + threadIdx.x; e < end; e += blockDim.x) {
        int d = dst[e];
        if (d >= lo && d < hi) {
            int pos = atomicAdd(&cursor[d], 1);
            sorted_src[pos] = src[e];
        }
    }
}

// hidden = coeffs[0]*x (fp32, natural layout); y0 split into two half-channel
// buffers: ya = half(dinv*x[:, 0:64]), yb = half(dinv*x[:, 64:128]).
// one thread per 8 channels (two float4 reads, one uint4 write).
__global__ void init_kernel(const float* __restrict__ x, const float* __restrict__ coeffs,
                            const float* __restrict__ dinv, float* __restrict__ hidden,
                            unsigned short* __restrict__ ya, unsigned short* __restrict__ yb,
                            int N) {
    int i = blockIdx.x * blockDim.x + threadIdx.x;   // over N*16 groups of 8 ch
    if (i >= N * 16) return;
    int node = i >> 4;
    int g = i & 15;            // 8-channel group within the 128-ch row
    float dv = dinv[node];
    float g0 = coeffs[0];
    const float4* xp = (const float4*)(x + (size_t)node * C + g * 8);
    float4 x0 = xp[0], x1 = xp[1];
    float4* hp = (float4*)(hidden + (size_t)node * C + g * 8);
    hp[0] = make_float4(g0 * x0.x, g0 * x0.y, g0 * x0.z, g0 * x0.w);
    hp[1] = make_float4(g0 * x1.x, g0 * x1.y, g0 * x1.z, g0 * x1.w);
    __half2 p0 = __floats2half2_rn(dv * x0.x, dv * x0.y);
    __half2 p1 = __floats2half2_rn(dv * x0.z, dv * x0.w);
    __half2 p2 = __floats2half2_rn(dv * x1.x, dv * x1.y);
    __half2 p3 = __floats2half2_rn(dv * x1.z, dv * x1.w);
    uint4 u;
    u.x = *reinterpret_cast<unsigned int*>(&p0);
    u.y = *reinterpret_cast<unsigned int*>(&p1);
    u.z = *reinterpret_cast<unsigned int*>(&p2);
    u.w = *reinterpret_cast<unsigned int*>(&p3);
    unsigned short* yp = (g < 8) ? ya : yb;
    int jj = g & 7;
    ((uint4*)yp)[(size_t)node * 8 + jj] = u;
}

// ---------------------------------------------------------------------------
__device__ __forceinline__ void acc8(float* a, uint4 u) {
    __half2* h = (__half2*)&u;
    #pragma unroll
    for (int i = 0; i < 4; ++i) {
        float2 f = __half22float2(h[i]);
        a[2 * i]     += f.x;
        a[2 * i + 1] += f.y;
    }
}

// one propagation step on a 64-channel half (row = 128 B = one cache line).
// block = 256 thr = 4 waves = 32 nodes (8 lanes/node, lane owns 16 B).
// hidden pointer is pre-offset to this half's channel block.
__global__ __launch_bounds__(256)
void prop_kernel(const unsigned short* __restrict__ yin, unsigned short* __restrict__ yout,
                 float* __restrict__ hidden, const float* __restrict__ coeffs, int k,
                 const int* __restrict__ offsets, const int* __restrict__ srcs,
                 const float* __restrict__ dinv, const int* __restrict__ perm, int n) {
    int t = threadIdx.x;
    int lane = t & 63;
    int grp  = lane >> 3;          // node within wave: 0..7
    int j    = lane & 7;           // 16-B slice within 128-B row
    int slot = blockIdx.x * 32 + (t >> 6) * 8 + grp;
    if (slot >= n) return;
    int v = perm[slot];
    int beg = offsets[v];
    int end = offsets[v + 1];
    float dv = dinv[v];
    float gamma = coeffs[k];

    const uint4* base = (const uint4*)yin;   // row = 8 uint4 (128 B)
    float A0[8] = {0,0,0,0,0,0,0,0};
    float A1[8] = {0,0,0,0,0,0,0,0};
    float A2[8] = {0,0,0,0,0,0,0,0};
    float A3[8] = {0,0,0,0,0,0,0,0};

    int e = beg;
    for (; e + 8 <= end; e += 8) {
        int s0 = srcs[e],     s1 = srcs[e + 1], s2 = srcs[e + 2], s3 = srcs[e + 3];
        int s4 = srcs[e + 4], s5 = srcs[e + 5], s6 = srcs[e + 6], s7 = srcs[e + 7];
        uint4 u0 = base[(size_t)s0 * 8 + j];
        uint4 u1 = base[(size_t)s1 * 8 + j];
        uint4 u2 = base[(size_t)s2 * 8 + j];
        uint4 u3 = base[(size_t)s3 * 8 + j];
        uint4 u4 = base[(size_t)s4 * 8 + j];
        uint4 u5 = base[(size_t)s5 * 8 + j];
        uint4 u6 = base[(size_t)s6 * 8 + j];
        uint4 u7 = base[(size_t)s7 * 8 + j];
        acc8(A0, u0); acc8(A1, u1); acc8(A2, u2); acc8(A3, u3);
        acc8(A0, u4); acc8(A1, u5); acc8(A2, u6); acc8(A3, u7);
    }
    for (; e + 4 <= end; e += 4) {
        int s0 = srcs[e], s1 = srcs[e + 1], s2 = srcs[e + 2], s3 = srcs[e + 3];
        uint4 u0 = base[(size_t)s0 * 8 + j];
        uint4 u1 = base[(size_t)s1 * 8 + j];
        uint4 u2 = base[(size_t)s2 * 8 + j];
        uint4 u3 = base[(size_t)s3 * 8 + j];
        acc8(A0, u0); acc8(A1, u1); acc8(A2, u2); acc8(A3, u3);
    }
    for (; e < end; ++e) {
        uint4 u = base[(size_t)srcs[e] * 8 + j];
        acc8(A0, u);
    }
    // self-loop term
    uint4 us = base[(size_t)v * 8 + j];
    acc8(A1, us);

    float xn[8];
    #pragma unroll
    for (int i = 0; i < 8; ++i)
        xn[i] = dv * ((A0[i] + A1[i]) + (A2[i] + A3[i]));

    // hidden RMW (pure stream; nontemporal to protect cache residency of y)
    f4_t* hp = (f4_t*)(hidden + (size_t)v * C + j * 8);
    f4_t h0 = __builtin_nontemporal_load(hp);
    f4_t h1 = __builtin_nontemporal_load(hp + 1);
    h0.x += gamma * xn[0]; h0.y += gamma * xn[1]; h0.z += gamma * xn[2]; h0.w += gamma * xn[3];
    h1.x += gamma * xn[4]; h1.y += gamma * xn[5]; h1.z += gamma * xn[6]; h1.w += gamma * xn[7];
    __builtin_nontemporal_store(h0, hp);
    __builtin_nontemporal_store(h1, hp + 1);

    // yout = half(dinv * xn)
    __half2 p0 = __floats2half2_rn(dv * xn[0], dv * xn[1]);
    __half2 p1 = __floats2half2_rn(dv * xn[2], dv * xn[3]);
    __half2 p2 = __floats2half2_rn(dv * xn[4], dv * xn[5]);
    __half2 p3 = __floats2half2_rn(dv * xn[6], dv * xn[7]);
    uint4 u;
    u.x = *reinterpret_cast<unsigned int*>(&p0);
    u.y = *reinterpret_cast<unsigned int*>(&p1);
    u.z = *reinterpret_cast<unsigned int*>(&p2);
    u.w = *reinterpret_cast<unsigned int*>(&p3);
    ((uint4*)yout)[(size_t)v * 8 + j] = u;
}

extern "C" void kernel_launch(void* const* d_in, const int* in_sizes, int n_in,
                              void* d_out, int out_size, void* d_ws, size_t ws_size,
                              hipStream_t stream) {
    const float* x      = (const float*)d_in[0];
    const float* coeffs = (const float*)d_in[1];
    const int*   edge   = (const int*)d_in[2];

    const int N = in_sizes[0] / C;          // 50000
    const int K = in_sizes[1] - 1;          // 10
    const int E = in_sizes[2] / 2;          // 1,600,000
    const int* src = edge;
    const int* dst = edge + E;

    char* ws = (char*)d_ws;
    auto alloc = [&](size_t bytes) -> void* {
        void* p = (void*)ws;
        ws += (bytes + 255) & ~(size_t)255;
        return p;
    };
    int*            cnt        = (int*)alloc((size_t)N * 4);
    int*            offsets    = (int*)alloc((size_t)(N + 1) * 4);
    int*            cursor     = (int*)alloc((size_t)N * 4);
    int*            sorted_src = (int*)alloc((size_t)E * 4);
    float*          dinv       = (float*)alloc((size_t)N * 4);
    int*            psum       = (int*)alloc(256 * 4);
    int*            bpre       = (int*)alloc(256 * 4);
    int*            hist       = (int*)alloc(NBUCK * 4);
    int*            bcur       = (int*)alloc(NBUCK * 4);
    int*            perm       = (int*)alloc((size_t)N * 4);
    unsigned short* bufA       = (unsigned short*)alloc((size_t)N * HC * 2);
    unsigned short* bufB       = (unsigned short*)alloc((size_t)N * HC * 2);
    unsigned short* bufC       = (unsigned short*)alloc((size_t)N * HC * 2);

    const int B = 256;
    const int nb = (N + 255) / 256;              // 196 scan blocks (<= 256)
    const int nps = (N + NSLICE - 1) / NSLICE;   // 6250 nodes per slice
    const int slice_grid = 8 * 256;              // 8 slices x 256 chunks

    zero_cnt_kernel<<<(N + B - 1) / B, B, 0, stream>>>(cnt, N);
    count_kernel<<<slice_grid, B, 0, stream>>>(dst, cnt, E, nps);

    scan_reduce_kernel<<<nb, 256, 0, stream>>>(cnt, psum, N);
    scan_partials_kernel<<<1, 256, 0, stream>>>(psum, bpre, offsets, N, nb);
    scan_apply_kernel<<<nb, 256, 0, stream>>>(cnt, bpre, offsets, cursor, dinv, N);

    hist_zero_kernel<<<1, NBUCK, 0, stream>>>(hist);
    hist_kernel<<<64, 256, 0, stream>>>(cnt, hist, N);
    hist_scan_kernel<<<1, NBUCK, 0, stream>>>(hist, bcur);
    perm_kernel<<<nb, 256, 0, stream>>>(cnt, bcur, perm, N);

    scatter_kernel<<<slice_grid, B, 0, stream>>>(src, dst, cursor, sorted_src, E, nps);
    init_kernel<<<((size_t)N * 16 + B - 1) / B, B, 0, stream>>>(x, coeffs, dinv,
                                                                (float*)d_out, bufA, bufB, N);

    const int pgrid = (N + 31) / 32;
    float* hidden = (float*)d_out;
    for (int p = 0; p < 2; ++p) {
        const unsigned short* yin = (p == 0) ? bufA : bufB;
        unsigned short* yout = bufC;
        float* hhalf = hidden + p * HC;
        for (int k = 1; k <= K; ++k) {
            prop_kernel<<<pgrid, B, 0, stream>>>(yin, yout, hhalf, coeffs, k,
                                                 offsets, sorted_src, dinv, perm, N);
            const unsigned short* tmp = yout;
            yout = (unsigned short*)((yin == bufC) ? yin : ((p == 0) ? bufA : bufB));
            yout = (unsigned short*)(( (const unsigned short*)yout == tmp) ? bufC : yout);
            yin = tmp;
            // simple ping-pong: yin/yout alternate between {bufA|bufB} and bufC
            yout = (unsigned short*)((yin == bufC) ? ((p == 0) ? bufA : bufB) : bufC);
        }
    }
}